// Round 7
// baseline (286.102 us; speedup 1.0000x reference)
//
#include <hip/hip_runtime.h>

#define Tt 1024
#define Dh 64
#define SCALE 0.125f

typedef __attribute__((ext_vector_type(4))) float f32x4;
typedef __attribute__((ext_vector_type(8))) short bf16x8;

__device__ inline unsigned short f2bf(float x){
  __bf16 h = (__bf16)x;                      // v_cvt_pk_bf16_f32 on gfx950 (RNE)
  return __builtin_bit_cast(unsigned short, h);
}
__device__ inline float bf2f(unsigned short h){
  return __uint_as_float(((unsigned)h) << 16);
}
__device__ inline ushort4 pack4(float4 f){
  ushort4 u; u.x=f2bf(f.x); u.y=f2bf(f.y); u.z=f2bf(f.z); u.w=f2bf(f.w); return u;
}
__device__ inline bf16x8 pack8(float4 a, float4 b){
  bf16x8 r;
  r[0]=(short)f2bf(a.x); r[1]=(short)f2bf(a.y); r[2]=(short)f2bf(a.z); r[3]=(short)f2bf(a.w);
  r[4]=(short)f2bf(b.x); r[5]=(short)f2bf(b.y); r[6]=(short)f2bf(b.z); r[7]=(short)f2bf(b.w);
  return r;
}
__device__ inline f32x4 mfma16(bf16x8 a, bf16x8 b, f32x4 c){
  return __builtin_amdgcn_mfma_f32_16x16x32_bf16(a, b, c, 0, 0, 0);
}
__device__ inline bf16x8 ldsfrag(const unsigned short (*lds)[68], int row, int col){
  const ushort4* p = (const ushort4*)&lds[row][col];
  ushort4 u0 = p[0], u1 = p[1];
  bf16x8 r;
  r[0]=(short)u0.x; r[1]=(short)u0.y; r[2]=(short)u0.z; r[3]=(short)u0.w;
  r[4]=(short)u1.x; r[5]=(short)u1.y; r[6]=(short)u1.z; r[7]=(short)u1.w;
  return r;
}
__device__ inline float fragsum(bf16x8 v){
  float s = 0.f;
#pragma unroll
  for (int i = 0; i < 8; ++i) s += bf2f((unsigned short)v[i]);
  return s;
}

// ---------------- Kernel 1: bias[bh][q][k] = sum_d Q[bh,q,d]*Ek[q,k,d] (bf16 out) ----------------
// T14: issue loads for kt+1 before compute(kt); ds_write after compute; dbuf LDS; 1 sync/tile.
__global__ __launch_bounds__(256) void k_qek(const float* __restrict__ Q,
                                             const float* __restrict__ EK,
                                             unsigned short* __restrict__ BIAS){
  __shared__ unsigned short ek[2][64][68];
  __shared__ unsigned short ot[4][16][68];
  const int qi = blockIdx.x;
  const int tid = threadIdx.x;
  const int w = tid >> 6, l = tid & 63, lr = l & 15, lg = l >> 4;
  const int sr = tid >> 2, sc = (tid & 3) * 16;
  const int or_ = l >> 2, oc = (l & 3) * 16;

  bf16x8 a0, a1;   // A rows bh = 16w+lr
  {
    const float4* q4 = (const float4*)(Q + ((size_t)(16*w + lr) * Tt + qi) * Dh);
    a0 = pack8(q4[lg*2],     q4[lg*2 + 1]);
    a1 = pack8(q4[8 + lg*2], q4[8 + lg*2 + 1]);
  }
  const float* ekq = EK + (size_t)qi * Tt * Dh;
  unsigned short* dst0 = BIAS + (size_t)(16*w + or_) * Tt * Tt + (size_t)qi * Tt + oc;

  float4 ereg[4];
  auto issueE = [&](int kt){
    const float4* g4 = (const float4*)(ekq + (size_t)kt*64*Dh + (size_t)sr*64 + sc);
    ereg[0]=g4[0]; ereg[1]=g4[1]; ereg[2]=g4[2]; ereg[3]=g4[3];
  };
  auto writeE = [&](int buf){
    ushort4* d4 = (ushort4*)&ek[buf][sr][sc];
    d4[0]=pack4(ereg[0]); d4[1]=pack4(ereg[1]); d4[2]=pack4(ereg[2]); d4[3]=pack4(ereg[3]);
  };

  issueE(0); writeE(0);
  __syncthreads();

  for (int kt = 0; kt < 16; ++kt){
    if (kt < 15) issueE(kt+1);                 // loads in flight during compute
    const unsigned short (*cur)[68] = ek[kt&1];
    f32x4 acc[4];
#pragma unroll
    for (int c = 0; c < 4; ++c){
      bf16x8 b0 = ldsfrag(cur, c*16 + lr, lg*8);
      bf16x8 b1 = ldsfrag(cur, c*16 + lr, lg*8 + 32);
      f32x4 z = {0.f,0.f,0.f,0.f};
      z = mfma16(a0, b0, z);
      z = mfma16(a1, b1, z);
      acc[c] = z;
    }
#pragma unroll
    for (int c = 0; c < 4; ++c)
#pragma unroll
      for (int j = 0; j < 4; ++j)
        ot[w][lg*4 + j][c*16 + lr] = f2bf(acc[c][j]);
    __builtin_amdgcn_wave_barrier();           // ot rows are wave-local
    {
      const ushort4* s4 = (const ushort4*)&ot[w][or_][oc];
      ushort4 u0=s4[0], u1=s4[1], u2=s4[2], u3=s4[3];
      ushort4* d4 = (ushort4*)(dst0 + kt*64);
      d4[0]=u0; d4[1]=u1; d4[2]=u2; d4[3]=u3;
    }
    __builtin_amdgcn_wave_barrier();
    if (kt < 15) writeE((kt+1)&1);             // vmcnt wait lands here, after compute
    __syncthreads();
  }
}

// ------- Kernel 2: P = exp((QK^T + bias)/8) -> ws (unnormalized, over bias); OUT = (P*V)/rowsum.
//         XCD swizzle; single LDS buffer + T14 split: write-early at tile head, issue-late after. ----
__global__ __launch_bounds__(256) void k_attn(const float* __restrict__ Q,
                                              const float* __restrict__ K,
                                              const float* __restrict__ V,
                                              unsigned short* WS,
                                              float* __restrict__ OUT){
  __shared__ unsigned short kt_[64][68];
  __shared__ unsigned short bt[64][68];
  __shared__ unsigned short pt[64][68];
  __shared__ unsigned short vt[64][68];
  const int bid = blockIdx.x;
  const int bh = (bid & 7) + ((bid >> 7) << 3);   // bid = (bh&7) + 8*((bh>>3)*16 + qtIdx)
  const int qt = ((bid >> 3) & 15) * 64;
  const int tid = threadIdx.x;
  const int w = tid >> 6, l = tid & 63, lr = l & 15, lg = l >> 4;
  const int sr = tid >> 2, sc = (tid & 3) * 16;
  const int vkb = (tid >> 4) * 4, vdb = (tid & 15) * 4;
  const int or_ = l >> 2, oc = (l & 3) * 16;

  bf16x8 a0, a1;   // A rows q = qt+16w+lr
  {
    const float4* q4 = (const float4*)(Q + ((size_t)bh * Tt + qt + 16*w + lr) * Dh);
    a0 = pack8(q4[lg*2],     q4[lg*2 + 1]);
    a1 = pack8(q4[8 + lg*2], q4[8 + lg*2 + 1]);
  }
  const float* kb = K + (size_t)bh * Tt * Dh;
  const float* vb = V + (size_t)bh * Tt * Dh;
  unsigned short* wsb = WS + (size_t)bh * Tt * Tt;

  float4 kreg[4]; ushort4 breg[4]; float vr[4][4];
  auto issue = [&](int kt){
    const float4* kg = (const float4*)(kb + (size_t)kt*64*Dh + (size_t)sr*64 + sc);
    kreg[0]=kg[0]; kreg[1]=kg[1]; kreg[2]=kg[2]; kreg[3]=kg[3];
    const ushort4* bg = (const ushort4*)(wsb + (size_t)(qt + sr)*Tt + (size_t)kt*64 + sc);
    breg[0]=bg[0]; breg[1]=bg[1]; breg[2]=bg[2]; breg[3]=bg[3];
    const float* vg = vb + (size_t)kt*64*Dh;
#pragma unroll
    for (int j = 0; j < 4; ++j){
      float4 f = *(const float4*)(vg + (size_t)(vkb + j)*64 + vdb);
      vr[j][0]=f.x; vr[j][1]=f.y; vr[j][2]=f.z; vr[j][3]=f.w;
    }
  };
  auto writeLDS = [&](){
    ushort4* kd = (ushort4*)&kt_[sr][sc];
    kd[0]=pack4(kreg[0]); kd[1]=pack4(kreg[1]); kd[2]=pack4(kreg[2]); kd[3]=pack4(kreg[3]);
    ushort4* bd = (ushort4*)&bt[sr][sc];
    bd[0]=breg[0]; bd[1]=breg[1]; bd[2]=breg[2]; bd[3]=breg[3];
#pragma unroll
    for (int i = 0; i < 4; ++i){
      ushort4 u;
      u.x=f2bf(vr[0][i]); u.y=f2bf(vr[1][i]); u.z=f2bf(vr[2][i]); u.w=f2bf(vr[3][i]);
      *(ushort4*)&vt[vdb + i][vkb] = u;
    }
  };

  float lsum[4] = {0.f,0.f,0.f,0.f};
  f32x4 oacc[4];
#pragma unroll
  for (int c = 0; c < 4; ++c) oacc[c] = (f32x4){0.f,0.f,0.f,0.f};

  issue(0);
  for (int kt = 0; kt < 16; ++kt){
    __syncthreads();                 // previous tile's LDS reads complete
    writeLDS();                      // loads arrived during previous compute
    __syncthreads();                 // staged
    if (kt < 15) issue(kt+1);        // overlap with compute below
#pragma unroll
    for (int c = 0; c < 4; ++c){
      bf16x8 b0 = ldsfrag(kt_, c*16 + lr, lg*8);
      bf16x8 b1 = ldsfrag(kt_, c*16 + lr, lg*8 + 32);
      f32x4 z = {0.f,0.f,0.f,0.f};
      z = mfma16(a0, b0, z);
      z = mfma16(a1, b1, z);
      int kl = c*16 + lr;
#pragma unroll
      for (int j = 0; j < 4; ++j){
        float s = (z[j] + bf2f(bt[16*w + lg*4 + j][kl])) * SCALE;
        float p = __expf(s);
        lsum[j] += p;
        pt[16*w + lg*4 + j][kl] = f2bf(p);
      }
    }
    __builtin_amdgcn_wave_barrier(); // pt rows are wave-local
    {
      const ushort4* s4 = (const ushort4*)&pt[16*w + or_][oc];
      ushort4 u0=s4[0], u1=s4[1], u2=s4[2], u3=s4[3];
      ushort4* d4 = (ushort4*)(wsb + (size_t)(qt + 16*w + or_)*Tt + kt*64 + oc);
      d4[0]=u0; d4[1]=u1; d4[2]=u2; d4[3]=u3;
    }
    bf16x8 p0 = ldsfrag(pt, 16*w + lr, lg*8);
    bf16x8 p1 = ldsfrag(pt, 16*w + lr, lg*8 + 32);
#pragma unroll
    for (int c = 0; c < 4; ++c){
      bf16x8 v0 = ldsfrag(vt, c*16 + lr, lg*8);
      bf16x8 v1 = ldsfrag(vt, c*16 + lr, lg*8 + 32);
      oacc[c] = mfma16(p0, v0, oacc[c]);
      oacc[c] = mfma16(p1, v1, oacc[c]);
    }
  }
  float rl[4];
#pragma unroll
  for (int j = 0; j < 4; ++j){
    float su = lsum[j];
    for (int o = 1; o < 16; o <<= 1) su += __shfl_xor(su, o, 64);
    rl[j] = 1.f / su;
  }
#pragma unroll
  for (int c = 0; c < 4; ++c)
#pragma unroll
    for (int j = 0; j < 4; ++j)
      OUT[((size_t)bh * Tt + qt + 16*w + lg*4 + j) * Dh + c*16 + lr] = oacc[c][j] * rl[j];
}

// ---------------- Kernel 3: OUT[bh,q,d] += (sum_k P*Ev)/rowsum(P) ----------------
// T14: Ev + P-frag prefetch one tile ahead; dbuf LDS; 1 sync/tile.
__global__ __launch_bounds__(256) void k_aev(const unsigned short* __restrict__ WS,
                                             const float* __restrict__ EV,
                                             float* __restrict__ OUT){
  __shared__ unsigned short evt[2][64][68];
  __shared__ float sums[64];
  const int qi = blockIdx.x;
  const int tid = threadIdx.x;
  const int w = tid >> 6, l = tid & 63, lr = l & 15, lg = l >> 4;
  const int vkb = (tid >> 4) * 4, vdb = (tid & 15) * 4;

  const unsigned short* arow = WS + (size_t)(16*w + lr) * Tt * Tt + (size_t)qi * Tt;
  const float* evq = EV + (size_t)qi * Tt * Dh;

  float vr[4][4];
  auto issueEV = [&](int kt){
    const float* vg = evq + (size_t)kt*64*Dh;
#pragma unroll
    for (int j = 0; j < 4; ++j){
      float4 f = *(const float4*)(vg + (size_t)(vkb + j)*64 + vdb);
      vr[j][0]=f.x; vr[j][1]=f.y; vr[j][2]=f.z; vr[j][3]=f.w;
    }
  };
  auto writeEV = [&](int buf){
#pragma unroll
    for (int i = 0; i < 4; ++i){
      ushort4 u;
      u.x=f2bf(vr[0][i]); u.y=f2bf(vr[1][i]); u.z=f2bf(vr[2][i]); u.w=f2bf(vr[3][i]);
      *(ushort4*)&evt[buf][vdb + i][vkb] = u;
    }
  };

  f32x4 acc[4];
#pragma unroll
  for (int c = 0; c < 4; ++c) acc[c] = (f32x4){0.f,0.f,0.f,0.f};
  float asum = 0.f;

  issueEV(0); writeEV(0);
  bf16x8 pa0 = *(const bf16x8*)(arow + lg*8);
  bf16x8 pa1 = *(const bf16x8*)(arow + 32 + lg*8);
  __syncthreads();

  for (int kt = 0; kt < 16; ++kt){
    bf16x8 na0, na1;
    if (kt < 15){
      issueEV(kt+1);
      na0 = *(const bf16x8*)(arow + (kt+1)*64 + lg*8);
      na1 = *(const bf16x8*)(arow + (kt+1)*64 + 32 + lg*8);
    }
    asum += fragsum(pa0) + fragsum(pa1);
    const unsigned short (*cur)[68] = evt[kt&1];
#pragma unroll
    for (int c = 0; c < 4; ++c){
      bf16x8 b0 = ldsfrag(cur, c*16 + lr, lg*8);
      bf16x8 b1 = ldsfrag(cur, c*16 + lr, lg*8 + 32);
      acc[c] = mfma16(pa0, b0, acc[c]);
      acc[c] = mfma16(pa1, b1, acc[c]);
    }
    if (kt < 15){
      writeEV((kt+1)&1);
      pa0 = na0; pa1 = na1;
    }
    __syncthreads();
  }
  asum += __shfl_xor(asum, 16, 64);
  asum += __shfl_xor(asum, 32, 64);
  if (lg == 0) sums[16*w + lr] = asum;   // wave-local broadcast
  __builtin_amdgcn_wave_barrier();

#pragma unroll
  for (int c = 0; c < 4; ++c)
#pragma unroll
    for (int j = 0; j < 4; ++j){
      int bh = 16*w + lg*4 + j;
      float rl = 1.f / sums[bh];
      size_t idx = ((size_t)bh * Tt + qi) * Dh + c*16 + lr;
      OUT[idx] += acc[c][j] * rl;
    }
}

extern "C" void kernel_launch(void* const* d_in, const int* in_sizes, int n_in,
                              void* d_out, int out_size, void* d_ws, size_t ws_size,
                              hipStream_t stream){
  const float* Q  = (const float*)d_in[0];
  const float* K  = (const float*)d_in[1];
  const float* V  = (const float*)d_in[2];
  const float* EK = (const float*)d_in[3];
  const float* EV = (const float*)d_in[4];
  float* OUT = (float*)d_out;
  unsigned short* WS = (unsigned short*)d_ws;

  if (ws_size < (size_t)64 * Tt * Tt * sizeof(unsigned short)) return;

  k_qek <<<dim3(1024), dim3(256), 0, stream>>>(Q, EK, WS);
  k_attn<<<dim3(1024), dim3(256), 0, stream>>>(Q, K, V, WS, OUT);
  k_aev <<<dim3(1024), dim3(256), 0, stream>>>(WS, EV, OUT);
}